// Round 2
// baseline (65.220 us; speedup 1.0000x reference)
//
#include <hip/hip_runtime.h>
#include <hip/hip_bf16.h>
#include <math.h>

// Problem constants (fixed by setup_inputs): xyz1, xyz2: (8, 4096, 3) fp32.
#define BB 8
#define NN 4096
#define NQ (BB * NN)          // queries per direction = 32768
#define CHUNK 512             // refs staged per block
#define NCHUNK (NN / CHUNK)   // 8
#define QPT 4                 // queries per thread
#define TPB 256
#define QPB (TPB * QPT)       // 1024 queries per block
#define NQBLK (NQ / QPB)      // 32 query-blocks per direction
#define ALPHA 1000.0f
#define EPS 1e-6f

// ---------------------------------------------------------------------------
// Kernel 1: brute-force argmin, split over ref-chunks, combined via
// atomicMin on a monotonic packed (dist_bits, idx) u64 key (deterministic).
// val = |r|^2 - 2*(q.r)  (== |q-r|^2 - |q|^2; same argmin as reference)
// ---------------------------------------------------------------------------
__global__ __launch_bounds__(TPB) void k_argmin(const float* __restrict__ xyz1,
                                                const float* __restrict__ xyz2,
                                                unsigned long long* __restrict__ pk) {
    __shared__ float4 tile[CHUNK];

    const int dir   = blockIdx.z;                 // 0: q=xyz1 ref=xyz2 ; 1: swapped
    const int qblk  = blockIdx.x;                 // 0..NQBLK-1
    const int chunk = blockIdx.y;                 // 0..NCHUNK-1
    const int t     = threadIdx.x;

    const float* __restrict__ Qp = dir ? xyz2 : xyz1;
    const float* __restrict__ Rp = dir ? xyz1 : xyz2;

    const int qbase = qblk * QPB;                 // within this dir's B*N query space
    const int b     = qbase / NN;                 // whole block is in one batch
    const int qrow0 = qbase - b * NN;

    // ---- stage this chunk's refs into LDS as (x, y, z, |r|^2) ----
    const float* __restrict__ Rb = Rp + (size_t)b * NN * 3 + (size_t)chunk * CHUNK * 3;
    for (int s = t; s < CHUNK; s += TPB) {
        float rx = Rb[3 * s + 0];
        float ry = Rb[3 * s + 1];
        float rz = Rb[3 * s + 2];
        tile[s] = make_float4(rx, ry, rz, fmaf(rx, rx, fmaf(ry, ry, rz * rz)));
    }
    __syncthreads();

    // ---- load QPT queries (stride TPB keeps loads coalesced) ----
    const float* __restrict__ Qb = Qp + (size_t)b * NN * 3;
    float m2x[QPT], m2y[QPT], m2z[QPT], vmin[QPT];
    int vidx[QPT];
#pragma unroll
    for (int q = 0; q < QPT; ++q) {
        const int qi = qrow0 + q * TPB + t;
        float qx = Qb[3 * qi + 0];
        float qy = Qb[3 * qi + 1];
        float qz = Qb[3 * qi + 2];
        m2x[q] = -2.0f * qx;
        m2y[q] = -2.0f * qy;
        m2z[q] = -2.0f * qz;
        vmin[q] = INFINITY;
        vidx[q] = 0;
    }

    const int jg = chunk * CHUNK;
#pragma unroll 4
    for (int j = 0; j < CHUNK; ++j) {
        const float4 r = tile[j];   // uniform address -> LDS broadcast, no conflicts
#pragma unroll
        for (int q = 0; q < QPT; ++q) {
            // 3 FMAs per eval
            float val = fmaf(m2x[q], r.x, fmaf(m2y[q], r.y, fmaf(m2z[q], r.z, r.w)));
            bool lt   = val < vmin[q];           // strict '<' => first-occurrence ties
            vidx[q]   = lt ? (jg + j) : vidx[q];
            vmin[q]   = fminf(val, vmin[q]);
        }
    }

    // ---- combine across chunks: monotonic float->uint map, pack with idx ----
#pragma unroll
    for (int q = 0; q < QPT; ++q) {
        const int qi = qrow0 + q * TPB + t;
        unsigned ub = __float_as_uint(vmin[q]);
        ub = (ub & 0x80000000u) ? ~ub : (ub | 0x80000000u);
        unsigned long long key =
            ((unsigned long long)ub << 32) | (unsigned long long)(unsigned)vidx[q];
        atomicMin(&pk[(size_t)dir * NQ + (size_t)b * NN + qi], key);
    }
}

// ---------------------------------------------------------------------------
// Kernel 2: histogram of chosen NN indices per (dir, batch).
// ---------------------------------------------------------------------------
__global__ __launch_bounds__(TPB) void k_count(const unsigned long long* __restrict__ pk,
                                               unsigned int* __restrict__ cnt) {
    const int gid = blockIdx.x * TPB + threadIdx.x;      // 0 .. 2*NQ-1
    const unsigned idx = (unsigned)(pk[gid] & 0xFFFFFFFFu);
    // (dir*BB + b) = gid >> 12   (NN == 4096 == 2^12)
    atomicAdd(&cnt[((unsigned)(gid >> 12) << 12) + idx], 1u);
}

// ---------------------------------------------------------------------------
// Kernel 3: per-query loss term + block partial sums (deterministic tree).
// dist recomputed exactly as reference: sum((q - r_idx)^2).
// ---------------------------------------------------------------------------
__device__ inline float block_reduce_sum(float v) {
    for (int o = 32; o > 0; o >>= 1) v += __shfl_down(v, o, 64);
    __shared__ float wsum[TPB / 64];
    const int lane = threadIdx.x & 63;
    const int w    = threadIdx.x >> 6;
    if (lane == 0) wsum[w] = v;
    __syncthreads();
    float r = 0.0f;
    if (threadIdx.x == 0) {
#pragma unroll
        for (int i = 0; i < TPB / 64; ++i) r += wsum[i];
    }
    return r;
}

__global__ __launch_bounds__(TPB) void k_loss(const float* __restrict__ xyz1,
                                              const float* __restrict__ xyz2,
                                              const unsigned long long* __restrict__ pk,
                                              const unsigned int* __restrict__ cnt,
                                              float* __restrict__ part) {
    const int gid = blockIdx.x * TPB + threadIdx.x;      // 0 .. 2*NQ-1
    const int dir = gid >> 15;                           // / NQ
    const int rem = gid & (NQ - 1);
    const int b   = rem >> 12;
    const int i   = rem & (NN - 1);

    const float* __restrict__ Qp = dir ? xyz2 : xyz1;
    const float* __restrict__ Rp = dir ? xyz1 : xyz2;

    const unsigned idx = (unsigned)(pk[gid] & 0xFFFFFFFFu);

    const float* q = Qp + ((size_t)b * NN + i) * 3;
    const float* r = Rp + ((size_t)b * NN + idx) * 3;
    const float dx = q[0] - r[0];
    const float dy = q[1] - r[1];
    const float dz = q[2] - r[2];
    const float d  = dx * dx + dy * dy + dz * dz;

    const float w    = 1.0f / ((float)cnt[((unsigned)(gid >> 12) << 12) + idx] + EPS);
    const float term = 1.0f - expf(-ALPHA * d) * w;

    const float s = block_reduce_sum(term);
    if (threadIdx.x == 0) part[blockIdx.x] = s;
}

// ---------------------------------------------------------------------------
// Kernel 4: final reduction of 256 partials -> scalar mean.
// ---------------------------------------------------------------------------
__global__ __launch_bounds__(TPB) void k_final(const float* __restrict__ part,
                                               float* __restrict__ out) {
    float v = part[threadIdx.x];                 // exactly 256 partials
    const float s = block_reduce_sum(v);
    if (threadIdx.x == 0) out[0] = s * (1.0f / (float)(2 * NQ));
}

// ---------------------------------------------------------------------------
extern "C" void kernel_launch(void* const* d_in, const int* in_sizes, int n_in,
                              void* d_out, int out_size, void* d_ws, size_t ws_size,
                              hipStream_t stream) {
    const float* xyz1 = (const float*)d_in[0];
    const float* xyz2 = (const float*)d_in[1];
    float* out = (float*)d_out;

    // workspace layout
    char* ws = (char*)d_ws;
    unsigned long long* pk  = (unsigned long long*)ws;               // 2*NQ u64 = 512 KiB
    unsigned int*       cnt = (unsigned int*)(ws + 2 * NQ * 8);      // 2*NQ u32 = 256 KiB
    float*              prt = (float*)(ws + 2 * NQ * 8 + 2 * NQ * 4); // 256 floats

    hipMemsetAsync(pk, 0xFF, (size_t)2 * NQ * 8, stream);   // +inf keys
    hipMemsetAsync(cnt, 0x00, (size_t)2 * NQ * 4, stream);  // zero counts

    k_argmin<<<dim3(NQBLK, NCHUNK, 2), TPB, 0, stream>>>(xyz1, xyz2, pk);
    k_count<<<(2 * NQ) / TPB, TPB, 0, stream>>>(pk, cnt);
    k_loss<<<(2 * NQ) / TPB, TPB, 0, stream>>>(xyz1, xyz2, pk, cnt, prt);
    k_final<<<1, TPB, 0, stream>>>(prt, out);
}

// Round 4
// 57.665 us; speedup vs baseline: 1.1310x; 1.1310x over previous
//
#include <hip/hip_runtime.h>
#include <hip/hip_bf16.h>
#include <math.h>

// Problem constants (fixed by setup_inputs): xyz1, xyz2: (8, 4096, 3) fp32.
#define BB 8
#define NN 4096
#define NQ (BB * NN)          // queries per direction = 32768
#define CHUNK 128             // refs staged per block
#define NCHUNK (NN / CHUNK)   // 32
#define QPT 8                 // queries per thread (4 f32x2 pairs)
#define NPAIR (QPT / 2)       // 4
#define TPB 256
#define QPB (TPB * QPT)       // 2048 queries per block
#define NQBLK (NQ / QPB)      // 16 query-blocks per direction
#define ALPHA 1000.0f
#define EPS 1e-6f

typedef float f32x2 __attribute__((ext_vector_type(2)));

// ---------------------------------------------------------------------------
// Kernel 1: brute-force argmin over ref-chunks. 2 queries packed per f32x2 so
// the 3 distance FMAs become v_pk_fma_f32 (dual-issue fp32). Refs are staged
// broadcast-duplicated in LDS: tileA[j]={x,x,y,y}, tileB[j]={z,z,w,w} with
// w=|r|^2. val = |r|^2 - 2*(q.r) shares its argmin with |q-r|^2.
// Cross-chunk combine: atomicMin on u32 key = (bits(d) & ~0xFFF) | idx,
// d = val + |q|^2 >= 0 (positive floats order as uints; idx in low 12 bits
// breaks 2^-11-relative near-ties toward the first occurrence).
// ---------------------------------------------------------------------------
__global__ __launch_bounds__(TPB, 4) void k_argmin(const float* __restrict__ xyz1,
                                                   const float* __restrict__ xyz2,
                                                   unsigned int* __restrict__ pk) {
    __shared__ float4 tileA[CHUNK];   // {x,x,y,y}
    __shared__ float4 tileB[CHUNK];   // {z,z,w,w}

    const int dir   = blockIdx.z;                 // 0: q=xyz1 ref=xyz2 ; 1: swapped
    const int qblk  = blockIdx.x;                 // 0..NQBLK-1
    const int chunk = blockIdx.y;                 // 0..NCHUNK-1
    const int t     = threadIdx.x;

    const float* __restrict__ Qp = dir ? xyz2 : xyz1;
    const float* __restrict__ Rp = dir ? xyz1 : xyz2;

    const int qbase = qblk * QPB;                 // within this dir's B*N query space
    const int b     = qbase / NN;                 // whole block is in one batch
    const int qrow0 = qbase - b * NN;

    // ---- stage this chunk's refs (duplicated halves) ----
    const float* __restrict__ Rb = Rp + (size_t)b * NN * 3 + (size_t)chunk * CHUNK * 3;
    if (t < CHUNK) {
        float rx = Rb[3 * t + 0];
        float ry = Rb[3 * t + 1];
        float rz = Rb[3 * t + 2];
        float rw = fmaf(rx, rx, fmaf(ry, ry, rz * rz));
        tileA[t] = make_float4(rx, rx, ry, ry);
        tileB[t] = make_float4(rz, rz, rw, rw);
    }
    __syncthreads();

    // ---- load QPT queries; pack pair p = queries (k=2p, k=2p+1) ----
    const float* __restrict__ Qb = Qp + (size_t)b * NN * 3;
    f32x2 m2x[NPAIR], m2y[NPAIR], m2z[NPAIR];
    float q2[QPT], vmin[QPT];
    int   vidx[QPT];
#pragma unroll
    for (int p = 0; p < NPAIR; ++p) {
        const int ka = 2 * p, kb = 2 * p + 1;
        const int qa = qrow0 + ka * TPB + t;
        const int qb = qrow0 + kb * TPB + t;
        float ax = Qb[3 * qa + 0], ay = Qb[3 * qa + 1], az = Qb[3 * qa + 2];
        float bx = Qb[3 * qb + 0], by = Qb[3 * qb + 1], bz = Qb[3 * qb + 2];
        m2x[p] = (f32x2){-2.0f * ax, -2.0f * bx};
        m2y[p] = (f32x2){-2.0f * ay, -2.0f * by};
        m2z[p] = (f32x2){-2.0f * az, -2.0f * bz};
        q2[ka] = fmaf(ax, ax, fmaf(ay, ay, az * az));
        q2[kb] = fmaf(bx, bx, fmaf(by, by, bz * bz));
        vmin[ka] = INFINITY; vmin[kb] = INFINITY;
        vidx[ka] = 0;        vidx[kb] = 0;
    }

    const int jg = chunk * CHUNK;
#pragma unroll 4
    for (int j = 0; j < CHUNK; ++j) {
        const float4 a = tileA[j];    // uniform address -> broadcast
        const float4 bb4 = tileB[j];
        const f32x2 xd = (f32x2){a.x, a.y};     // actually {x,x}
        const f32x2 yd = (f32x2){a.z, a.w};     // {y,y}
        const f32x2 zd = (f32x2){bb4.x, bb4.y}; // {z,z}
        const f32x2 wd = (f32x2){bb4.z, bb4.w}; // {w,w}
        const int gj = jg + j;
#pragma unroll
        for (int p = 0; p < NPAIR; ++p) {
            // 3 packed FMAs = 6 scalar FMAs for 2 queries
            f32x2 acc = m2z[p] * zd + wd;
            acc = m2y[p] * yd + acc;
            acc = m2x[p] * xd + acc;
            const int ka = 2 * p, kb = 2 * p + 1;
            bool lt0 = acc.x < vmin[ka];
            vidx[ka] = lt0 ? gj : vidx[ka];
            vmin[ka] = fminf(acc.x, vmin[ka]);
            bool lt1 = acc.y < vmin[kb];
            vidx[kb] = lt1 ? gj : vidx[kb];
            vmin[kb] = fminf(acc.y, vmin[kb]);
        }
    }

    // ---- combine across chunks: positive-float key with idx in low 12 bits ----
    unsigned int* __restrict__ pkb = pk + (size_t)(dir * BB + b) * NN;
#pragma unroll
    for (int k = 0; k < QPT; ++k) {
        const int qk = qrow0 + k * TPB + t;
        float d = fmaxf(vmin[k] + q2[k], 0.0f);        // true sq-dist, clamp fp dust
        unsigned key = (__float_as_uint(d) & 0xFFFFF000u) | (unsigned)vidx[k];
        atomicMin(&pkb[qk], key);
    }
}

// ---------------------------------------------------------------------------
// Kernel 2: histogram of chosen NN indices per (dir, batch).
// ---------------------------------------------------------------------------
__global__ __launch_bounds__(TPB) void k_count(const unsigned int* __restrict__ pk,
                                               unsigned int* __restrict__ cnt) {
    const int gid = blockIdx.x * TPB + threadIdx.x;      // 0 .. 2*NQ-1
    const unsigned idx = pk[gid] & 0xFFFu;
    // (dir*BB + b) = gid >> 12   (NN == 4096 == 2^12)
    atomicAdd(&cnt[((unsigned)(gid >> 12) << 12) + idx], 1u);
}

// ---------------------------------------------------------------------------
// Kernel 3: per-query loss term + block partial sums (deterministic tree).
// dist recomputed exactly as reference: sum((q - r_idx)^2).
// ---------------------------------------------------------------------------
__device__ inline float block_reduce_sum(float v) {
    for (int o = 32; o > 0; o >>= 1) v += __shfl_down(v, o, 64);
    __shared__ float wsum[TPB / 64];
    const int lane = threadIdx.x & 63;
    const int w    = threadIdx.x >> 6;
    if (lane == 0) wsum[w] = v;
    __syncthreads();
    float r = 0.0f;
    if (threadIdx.x == 0) {
#pragma unroll
        for (int i = 0; i < TPB / 64; ++i) r += wsum[i];
    }
    return r;
}

__global__ __launch_bounds__(TPB) void k_loss(const float* __restrict__ xyz1,
                                              const float* __restrict__ xyz2,
                                              const unsigned int* __restrict__ pk,
                                              const unsigned int* __restrict__ cnt,
                                              float* __restrict__ part) {
    const int gid = blockIdx.x * TPB + threadIdx.x;      // 0 .. 2*NQ-1
    const int dir = gid >> 15;                           // / NQ
    const int rem = gid & (NQ - 1);
    const int b   = rem >> 12;
    const int i   = rem & (NN - 1);

    const float* __restrict__ Qp = dir ? xyz2 : xyz1;
    const float* __restrict__ Rp = dir ? xyz1 : xyz2;

    const unsigned idx = pk[gid] & 0xFFFu;

    const float* q = Qp + ((size_t)b * NN + i) * 3;
    const float* r = Rp + ((size_t)b * NN + idx) * 3;
    const float dx = q[0] - r[0];
    const float dy = q[1] - r[1];
    const float dz = q[2] - r[2];
    const float d  = dx * dx + dy * dy + dz * dz;

    const float w    = 1.0f / ((float)cnt[((unsigned)(gid >> 12) << 12) + idx] + EPS);
    const float term = 1.0f - expf(-ALPHA * d) * w;

    const float s = block_reduce_sum(term);
    if (threadIdx.x == 0) part[blockIdx.x] = s;
}

// ---------------------------------------------------------------------------
// Kernel 4: final reduction of 256 partials -> scalar mean.
// ---------------------------------------------------------------------------
__global__ __launch_bounds__(TPB) void k_final(const float* __restrict__ part,
                                               float* __restrict__ out) {
    float v = part[threadIdx.x];                 // exactly 256 partials
    const float s = block_reduce_sum(v);
    if (threadIdx.x == 0) out[0] = s * (1.0f / (float)(2 * NQ));
}

// ---------------------------------------------------------------------------
extern "C" void kernel_launch(void* const* d_in, const int* in_sizes, int n_in,
                              void* d_out, int out_size, void* d_ws, size_t ws_size,
                              hipStream_t stream) {
    const float* xyz1 = (const float*)d_in[0];
    const float* xyz2 = (const float*)d_in[1];
    float* out = (float*)d_out;

    // workspace layout (total ~513 KiB)
    char* ws = (char*)d_ws;
    unsigned int* pk  = (unsigned int*)ws;                            // 2*NQ u32 = 256 KiB
    unsigned int* cnt = (unsigned int*)(ws + 2 * NQ * 4);             // 2*NQ u32 = 256 KiB
    float*        prt = (float*)(ws + 2 * NQ * 4 + 2 * NQ * 4);       // 256 floats

    hipMemsetAsync(pk, 0xFF, (size_t)2 * NQ * 4, stream);   // max keys
    hipMemsetAsync(cnt, 0x00, (size_t)2 * NQ * 4, stream);  // zero counts

    k_argmin<<<dim3(NQBLK, NCHUNK, 2), TPB, 0, stream>>>(xyz1, xyz2, pk);
    k_count<<<(2 * NQ) / TPB, TPB, 0, stream>>>(pk, cnt);
    k_loss<<<(2 * NQ) / TPB, TPB, 0, stream>>>(xyz1, xyz2, pk, cnt, prt);
    k_final<<<1, TPB, 0, stream>>>(prt, out);
}

// Round 6
// 57.259 us; speedup vs baseline: 1.1390x; 1.0071x over previous
//
#include <hip/hip_runtime.h>
#include <hip/hip_bf16.h>
#include <math.h>

// Problem constants (fixed by setup_inputs): xyz1, xyz2: (8, 4096, 3) fp32.
#define BB 8
#define NN 4096
#define NQ (BB * NN)          // queries per direction = 32768
#define CHUNK 64              // refs scanned per block
#define NCHUNK (NN / CHUNK)   // 64
#define QPT 4                 // queries per thread (2 f32x2 pairs)
#define NPAIR (QPT / 2)       // 2
#define TPB 256
#define QPB (TPB * QPT)       // 1024 queries per block
#define NQBLK (NQ / QPB)      // 32 query-blocks per direction
#define ALPHA 1000.0f
#define EPS 1e-6f

typedef float f32x2 __attribute__((ext_vector_type(2)));

static __device__ __forceinline__ unsigned umin2(unsigned a, unsigned b) {
    return a < b ? a : b;
}

// ---------------------------------------------------------------------------
// Kernel 0: stage refs as float4 {x, y, z, |r|^2}. dir0 refs = xyz2, dir1 = xyz1.
// ---------------------------------------------------------------------------
__global__ __launch_bounds__(TPB) void k_prep(const float* __restrict__ xyz1,
                                              const float* __restrict__ xyz2,
                                              float4* __restrict__ R4) {
    const int gid = blockIdx.x * TPB + threadIdx.x;   // 0 .. 2*NQ-1
    const int dir = gid >> 15;
    const int rem = gid & (NQ - 1);
    const float* __restrict__ src = dir ? xyz1 : xyz2;
    const float x = src[3 * rem + 0];
    const float y = src[3 * rem + 1];
    const float z = src[3 * rem + 2];
    R4[gid] = make_float4(x, y, z, fmaf(x, x, fmaf(y, y, z * z)));
}

// ---------------------------------------------------------------------------
// Kernel 1: brute-force argmin. Refs streamed through SGPRs (uniform loads of
// the prepped float4), consumed by v_pk_fma_f32 with op_sel broadcasts:
//   d2 = {|r|^2 - 2 q.r} + |q|^2   (exact d^2 up to fp dust; >= 0)
// computed for 2 queries per instruction. Min-tracking on u32 keys:
//   key = (bits(d2) & 0xFFFFF000) | j    (positive floats order as uints;
// 12-lsb truncation breaks only 2^-11-relative near-ties, idx = low 12 bits).
// Cross-chunk combine via atomicMin(u32).
// ---------------------------------------------------------------------------
__global__ __launch_bounds__(TPB, 8) void k_argmin(const float* __restrict__ xyz1,
                                                   const float* __restrict__ xyz2,
                                                   const float4* __restrict__ R4,
                                                   unsigned int* __restrict__ pk) {
    const int dir   = blockIdx.z;                 // 0: q=xyz1 ref=xyz2 ; 1: swapped
    const int qblk  = blockIdx.x;                 // 0..NQBLK-1
    const int chunk = blockIdx.y;                 // 0..NCHUNK-1
    const int t     = threadIdx.x;

    const float* __restrict__ Qp = dir ? xyz2 : xyz1;

    const int qbase = qblk * QPB;
    const int b     = qbase / NN;                 // whole block in one batch
    const int qrow0 = qbase - b * NN;

    // ---- load QPT queries; pair p packs queries (2p, 2p+1) ----
    const float* __restrict__ Qb = Qp + (size_t)b * NN * 3;
    f32x2 m2x[NPAIR], m2y[NPAIR], m2z[NPAIR], q2[NPAIR];
    unsigned kmin[QPT];
#pragma unroll
    for (int p = 0; p < NPAIR; ++p) {
        const int qa = qrow0 + (2 * p) * TPB + t;
        const int qb = qrow0 + (2 * p + 1) * TPB + t;
        float ax = Qb[3 * qa + 0], ay = Qb[3 * qa + 1], az = Qb[3 * qa + 2];
        float bx = Qb[3 * qb + 0], by = Qb[3 * qb + 1], bz = Qb[3 * qb + 2];
        m2x[p] = (f32x2){-2.0f * ax, -2.0f * bx};
        m2y[p] = (f32x2){-2.0f * ay, -2.0f * by};
        m2z[p] = (f32x2){-2.0f * az, -2.0f * bz};
        q2[p]  = (f32x2){fmaf(ax, ax, fmaf(ay, ay, az * az)),
                         fmaf(bx, bx, fmaf(by, by, bz * bz))};
        kmin[2 * p] = 0xFFFFFFFFu;
        kmin[2 * p + 1] = 0xFFFFFFFFu;
    }

    // ---- scan this chunk's refs (uniform address -> s_load, SGPR operands) ----
    const float4* __restrict__ Rc = R4 + ((size_t)dir * NQ + (size_t)b * NN
                                          + (size_t)chunk * CHUNK);
    const int jg = chunk * CHUNK;

#pragma unroll 2
    for (int j = 0; j < CHUNK; j += 2) {
        const float4 r0 = Rc[j];
        const float4 r1 = Rc[j + 1];
        const f32x2 xy0 = (f32x2){r0.x, r0.y};
        const f32x2 zw0 = (f32x2){r0.z, r0.w};
        const f32x2 xy1 = (f32x2){r1.x, r1.y};
        const f32x2 zw1 = (f32x2){r1.z, r1.w};
        const unsigned j0 = (unsigned)(jg + j);
        const unsigned j1 = (unsigned)(jg + j + 1);
#pragma unroll
        for (int p = 0; p < NPAIR; ++p) {
            f32x2 accA, accB;
            // accA = m2z*z0 + w0 ; accA = m2y*y0 + accA ; accA = m2x*x0 + accA
            asm("v_pk_fma_f32 %0, %1, %2, %2 op_sel:[0,0,1] op_sel_hi:[1,0,1]"
                : "=v"(accA) : "v"(m2z[p]), "s"(zw0));
            asm("v_pk_fma_f32 %0, %1, %2, %3 op_sel:[0,1,0] op_sel_hi:[1,1,1]"
                : "=v"(accA) : "v"(m2y[p]), "s"(xy0), "v"(accA));
            asm("v_pk_fma_f32 %0, %1, %2, %3 op_sel:[0,0,0] op_sel_hi:[1,0,1]"
                : "=v"(accA) : "v"(m2x[p]), "s"(xy0), "v"(accA));
            asm("v_pk_add_f32 %0, %1, %2" : "=v"(accA) : "v"(accA), "v"(q2[p]));
            // same for ref j+1
            asm("v_pk_fma_f32 %0, %1, %2, %2 op_sel:[0,0,1] op_sel_hi:[1,0,1]"
                : "=v"(accB) : "v"(m2z[p]), "s"(zw1));
            asm("v_pk_fma_f32 %0, %1, %2, %3 op_sel:[0,1,0] op_sel_hi:[1,1,1]"
                : "=v"(accB) : "v"(m2y[p]), "s"(xy1), "v"(accB));
            asm("v_pk_fma_f32 %0, %1, %2, %3 op_sel:[0,0,0] op_sel_hi:[1,0,1]"
                : "=v"(accB) : "v"(m2x[p]), "s"(xy1), "v"(accB));
            asm("v_pk_add_f32 %0, %1, %2" : "=v"(accB) : "v"(accB), "v"(q2[p]));

            // keys: (bits & ~0xFFF) | j  -> v_and_or_b32 ; min across j, j+1
            const unsigned kA0 = (__float_as_uint(accA.x) & 0xFFFFF000u) | j0;
            const unsigned kA1 = (__float_as_uint(accA.y) & 0xFFFFF000u) | j0;
            const unsigned kB0 = (__float_as_uint(accB.x) & 0xFFFFF000u) | j1;
            const unsigned kB1 = (__float_as_uint(accB.y) & 0xFFFFF000u) | j1;
            kmin[2 * p]     = umin2(umin2(kA0, kB0), kmin[2 * p]);
            kmin[2 * p + 1] = umin2(umin2(kA1, kB1), kmin[2 * p + 1]);
        }
    }

    // ---- combine across chunks ----
    unsigned int* __restrict__ pkb = pk + (size_t)(dir * BB + b) * NN;
#pragma unroll
    for (int k = 0; k < QPT; ++k) {
        atomicMin(&pkb[qrow0 + k * TPB + t], kmin[k]);
    }
}

// ---------------------------------------------------------------------------
// Kernel 2: histogram of chosen NN indices per (dir, batch).
// ---------------------------------------------------------------------------
__global__ __launch_bounds__(TPB) void k_count(const unsigned int* __restrict__ pk,
                                               unsigned int* __restrict__ cnt) {
    const int gid = blockIdx.x * TPB + threadIdx.x;      // 0 .. 2*NQ-1
    const unsigned idx = pk[gid] & 0xFFFu;
    atomicAdd(&cnt[((unsigned)(gid >> 12) << 12) + idx], 1u);
}

// ---------------------------------------------------------------------------
// Kernel 3: per-query loss term + block partial sums (deterministic tree).
// dist recomputed exactly as reference: sum((q - r_idx)^2).
// ---------------------------------------------------------------------------
__device__ inline float block_reduce_sum(float v) {
    for (int o = 32; o > 0; o >>= 1) v += __shfl_down(v, o, 64);
    __shared__ float wsum[TPB / 64];
    const int lane = threadIdx.x & 63;
    const int w    = threadIdx.x >> 6;
    if (lane == 0) wsum[w] = v;
    __syncthreads();
    float r = 0.0f;
    if (threadIdx.x == 0) {
#pragma unroll
        for (int i = 0; i < TPB / 64; ++i) r += wsum[i];
    }
    return r;
}

__global__ __launch_bounds__(TPB) void k_loss(const float* __restrict__ xyz1,
                                              const float* __restrict__ xyz2,
                                              const unsigned int* __restrict__ pk,
                                              const unsigned int* __restrict__ cnt,
                                              float* __restrict__ part) {
    const int gid = blockIdx.x * TPB + threadIdx.x;      // 0 .. 2*NQ-1
    const int dir = gid >> 15;
    const int rem = gid & (NQ - 1);
    const int b   = rem >> 12;
    const int i   = rem & (NN - 1);

    const float* __restrict__ Qp = dir ? xyz2 : xyz1;
    const float* __restrict__ Rp = dir ? xyz1 : xyz2;

    const unsigned idx = pk[gid] & 0xFFFu;

    const float* q = Qp + ((size_t)b * NN + i) * 3;
    const float* r = Rp + ((size_t)b * NN + idx) * 3;
    const float dx = q[0] - r[0];
    const float dy = q[1] - r[1];
    const float dz = q[2] - r[2];
    const float d  = dx * dx + dy * dy + dz * dz;

    const float w    = 1.0f / ((float)cnt[((unsigned)(gid >> 12) << 12) + idx] + EPS);
    const float term = 1.0f - expf(-ALPHA * d) * w;

    const float s = block_reduce_sum(term);
    if (threadIdx.x == 0) part[blockIdx.x] = s;
}

// ---------------------------------------------------------------------------
// Kernel 4: final reduction of 256 partials -> scalar mean.
// ---------------------------------------------------------------------------
__global__ __launch_bounds__(TPB) void k_final(const float* __restrict__ part,
                                               float* __restrict__ out) {
    float v = part[threadIdx.x];                 // exactly 256 partials
    const float s = block_reduce_sum(v);
    if (threadIdx.x == 0) out[0] = s * (1.0f / (float)(2 * NQ));
}

// ---------------------------------------------------------------------------
extern "C" void kernel_launch(void* const* d_in, const int* in_sizes, int n_in,
                              void* d_out, int out_size, void* d_ws, size_t ws_size,
                              hipStream_t stream) {
    const float* xyz1 = (const float*)d_in[0];
    const float* xyz2 = (const float*)d_in[1];
    float* out = (float*)d_out;

    // workspace layout (~1.6 MiB total)
    char* ws = (char*)d_ws;
    unsigned int* pk  = (unsigned int*)ws;                      // 2*NQ u32 = 256 KiB
    unsigned int* cnt = (unsigned int*)(ws + 262144);           // 2*NQ u32 = 256 KiB
    float*        prt = (float*)(ws + 524288);                  // 256 floats (4 KiB resv)
    float4*       R4  = (float4*)(ws + 528384);                 // 2*NQ float4 = 1 MiB

    hipMemsetAsync(pk, 0xFF, (size_t)2 * NQ * 4, stream);   // max keys
    hipMemsetAsync(cnt, 0x00, (size_t)2 * NQ * 4, stream);  // zero counts

    k_prep<<<(2 * NQ) / TPB, TPB, 0, stream>>>(xyz1, xyz2, R4);
    k_argmin<<<dim3(NQBLK, NCHUNK, 2), TPB, 0, stream>>>(xyz1, xyz2, R4, pk);
    k_count<<<(2 * NQ) / TPB, TPB, 0, stream>>>(pk, cnt);
    k_loss<<<(2 * NQ) / TPB, TPB, 0, stream>>>(xyz1, xyz2, pk, cnt, prt);
    k_final<<<1, TPB, 0, stream>>>(prt, out);
}

// Round 7
// 44.514 us; speedup vs baseline: 1.4651x; 1.2863x over previous
//
#include <hip/hip_runtime.h>
#include <hip/hip_bf16.h>
#include <math.h>

// Problem constants: xyz1, xyz2: (8, 4096, 3) fp32.
#define BB 8
#define NN 4096
#define NQ (BB * NN)          // 32768 queries per direction
#define TPB 256
#define ALPHA 1000.0f
#define EPS 1e-6f

typedef short bf16x8 __attribute__((ext_vector_type(8)));
typedef float f32x4  __attribute__((ext_vector_type(4)));

__device__ static const unsigned __attribute__((aligned(16))) kZero16[4] = {0u, 0u, 0u, 0u};

static __device__ __forceinline__ unsigned umin2(unsigned a, unsigned b) { return a < b ? a : b; }

static __device__ __forceinline__ unsigned short f2bf(float v) {   // RNE fp32->bf16
    unsigned u = __float_as_uint(v);
    u += 0x7FFFu + ((u >> 16) & 1u);
    return (unsigned short)(u >> 16);
}
static __device__ __forceinline__ float bf2f(unsigned short h) {
    return __uint_as_float(((unsigned)h) << 16);
}

// ---------------------------------------------------------------------------
// Kernel 0: pack MFMA operands + init pk/cnt.
// Per point, a 16-slot bf16 k-vector (slots 16..31 of the K=32 MFMA are zero,
// supplied by kZero16 at load time). With qs = split(-2*xyz1), r = split(xyz2):
//   A slots: [qh0..2, qh0..2, ql0..2, ql0..2, q2h, q2l, 1, 1]
//   B slots: [rh0..2, rl0..2, rh0..2, rl0..2, 1, 1, r2h, r2l]
// => per-k products sum to (qh+ql).(rh+rl) + |q|^2 + |r|^2 = d~^2 (err ~3e-5).
// ---------------------------------------------------------------------------
__global__ __launch_bounds__(TPB) void k_prep(const float* __restrict__ xyz1,
                                              const float* __restrict__ xyz2,
                                              unsigned short* __restrict__ Amat,
                                              unsigned short* __restrict__ Bmat,
                                              unsigned int* __restrict__ pk,
                                              unsigned int* __restrict__ cnt) {
    const int gid = blockIdx.x * TPB + threadIdx.x;   // 0 .. 2*NQ-1
    pk[gid]  = 0xFFFFFFFFu;
    cnt[gid] = 0u;

    const int side = gid >> 15;                       // 0: A-side (xyz1), 1: B-side (xyz2)
    const int rem  = gid & (NQ - 1);                  // b*NN + point
    const float* __restrict__ src = side ? xyz2 : xyz1;
    const float x = src[3 * rem + 0];
    const float y = src[3 * rem + 1];
    const float z = src[3 * rem + 2];
    const float n2 = fmaf(x, x, fmaf(y, y, z * z));
    const unsigned short n2h = f2bf(n2);
    const unsigned short n2l = f2bf(n2 - bf2f(n2h));
    const unsigned one2 = 0x3F803F80u;                // {1.0bf16, 1.0bf16}

    uint4 w0, w1;
    if (side == 0) {
        const float sx = -2.0f * x, sy = -2.0f * y, sz = -2.0f * z;
        const unsigned h0 = f2bf(sx), h1 = f2bf(sy), h2 = f2bf(sz);
        const unsigned l0 = f2bf(sx - bf2f((unsigned short)h0));
        const unsigned l1 = f2bf(sy - bf2f((unsigned short)h1));
        const unsigned l2 = f2bf(sz - bf2f((unsigned short)h2));
        w0 = make_uint4(h0 | (h1 << 16), h2 | (h0 << 16), h1 | (h2 << 16), l0 | (l1 << 16));
        w1 = make_uint4(l2 | (l0 << 16), l1 | (l2 << 16),
                        (unsigned)n2h | ((unsigned)n2l << 16), one2);
        uint4* dst = (uint4*)(Amat + (size_t)rem * 16);
        dst[0] = w0; dst[1] = w1;
    } else {
        const unsigned h0 = f2bf(x), h1 = f2bf(y), h2 = f2bf(z);
        const unsigned l0 = f2bf(x - bf2f((unsigned short)h0));
        const unsigned l1 = f2bf(y - bf2f((unsigned short)h1));
        const unsigned l2 = f2bf(z - bf2f((unsigned short)h2));
        w0 = make_uint4(h0 | (h1 << 16), h2 | (l0 << 16), l1 | (l2 << 16), h0 | (h1 << 16));
        w1 = make_uint4(h2 | (l0 << 16), l1 | (l2 << 16),
                        one2, (unsigned)n2h | ((unsigned)n2l << 16));
        uint4* dst = (uint4*)(Bmat + (size_t)rem * 16);
        dst[0] = w0; dst[1] = w1;
    }
}

static __device__ __forceinline__ bf16x8 load_frag(const unsigned short* rowbase, int grp) {
    // k-slots grp*8..grp*8+7; slots >=16 are zero.
    const unsigned short* p = (grp < 2) ? (rowbase + grp * 8)
                                        : (const unsigned short*)kZero16;
    return *(const bf16x8*)p;
}

// ---------------------------------------------------------------------------
// Kernel 1: MFMA argmin. Per batch b, score tiles D[i][j] = d~^2(x1_i, x2_j)
// via mfma_f32_16x16x32_bf16 (C layout: col=lane&15, row=(lane>>4)*4+reg).
// Row-mins feed dir0 (xyz1 queries), col-mins feed dir1 (xyz2 queries).
// Keys: (bits(D) & 0xFFFFF000) | index  (positive floats order as uints;
// truncation breaks only 2^-11-relative near-ties toward smaller index).
// kC = kR + (i - j) rewrites the low 12 bits from j to i exactly (i,j < 4096).
// Block: 4 waves x 64 rows = 256 rows; 256 cols swept in 16 col-tiles.
// ---------------------------------------------------------------------------
__global__ __launch_bounds__(TPB, 4) void k_argmin(const unsigned short* __restrict__ Amat,
                                                   const unsigned short* __restrict__ Bmat,
                                                   unsigned int* __restrict__ pk) {
    const int cchunk = blockIdx.x;                // 0..15 (256-col chunk)
    const int rblk   = blockIdx.y;                // 0..15 (256-row block)
    const int b      = blockIdx.z;                // 0..7
    const int tid    = threadIdx.x;
    const int lane   = tid & 63;
    const int wv     = tid >> 6;
    const int c      = lane & 15;
    const int grp    = lane >> 4;

    const int row0 = rblk * 256 + wv * 64;        // wave's first row (within b)
    const int col0 = cchunk * 256;

    const unsigned short* __restrict__ Ab = Amat + (size_t)b * NN * 16;
    const unsigned short* __restrict__ Bb = Bmat + (size_t)b * NN * 16;

    // A fragments for this wave's 4 row-tiles (register-resident, reused x16)
    bf16x8 af0 = load_frag(Ab + (size_t)(row0 +  0 + c) * 16, grp);
    bf16x8 af1 = load_frag(Ab + (size_t)(row0 + 16 + c) * 16, grp);
    bf16x8 af2 = load_frag(Ab + (size_t)(row0 + 32 + c) * 16, grp);
    bf16x8 af3 = load_frag(Ab + (size_t)(row0 + 48 + c) * 16, grp);

    unsigned rowkey[16];
#pragma unroll
    for (int i = 0; i < 16; ++i) rowkey[i] = 0xFFFFFFFFu;

    unsigned jc = (unsigned)(col0 + c);           // this lane's global col
    const unsigned irbase = (unsigned)(row0 + grp * 4);

    unsigned int* __restrict__ pkrow = pk + (size_t)b * NN;            // dir0
    unsigned int* __restrict__ pkcol = pk + (size_t)NQ + (size_t)b * NN; // dir1

    const f32x4 zz = {0.f, 0.f, 0.f, 0.f};

    for (int cc = 0; cc < 16; ++cc) {
        const bf16x8 bf = load_frag(Bb + (size_t)jc * 16, grp);
        unsigned colkey = 0xFFFFFFFFu;
        const unsigned irdel = irbase - jc;       // wraps; sum is exact mod 2^32

#pragma unroll
        for (int rt = 0; rt < 4; ++rt) {
            const bf16x8 af = (rt == 0) ? af0 : (rt == 1) ? af1 : (rt == 2) ? af2 : af3;
            f32x4 acc = __builtin_amdgcn_mfma_f32_16x16x32_bf16(af, bf, zz, 0, 0, 0);
            const unsigned d2 = irdel + (unsigned)(rt * 16);
#pragma unroll
            for (int k = 0; k < 4; ++k) {
                const unsigned kR = (__float_as_uint(acc[k]) & 0xFFFFF000u) | jc;
                rowkey[rt * 4 + k] = umin2(rowkey[rt * 4 + k], kR);
                const unsigned kC = kR + d2 + (unsigned)k;   // low 12 bits -> row i
                colkey = umin2(colkey, kC);
            }
        }
        // col-min: reduce across the 4 lane-groups (same col set)
        colkey = umin2(colkey, (unsigned)__shfl_xor((int)colkey, 16, 64));
        colkey = umin2(colkey, (unsigned)__shfl_xor((int)colkey, 32, 64));
        if (grp == 0) atomicMin(&pkcol[jc], colkey);
        jc += 16;
    }

    // row-min: reduce each row's key across the 16 lanes of its group
#pragma unroll
    for (int rr = 0; rr < 16; ++rr) {
        unsigned v = rowkey[rr];
        v = umin2(v, (unsigned)__shfl_xor((int)v, 1, 64));
        v = umin2(v, (unsigned)__shfl_xor((int)v, 2, 64));
        v = umin2(v, (unsigned)__shfl_xor((int)v, 4, 64));
        v = umin2(v, (unsigned)__shfl_xor((int)v, 8, 64));
        if (c == 0) {
            const int row = row0 + (rr >> 2) * 16 + grp * 4 + (rr & 3);
            atomicMin(&pkrow[row], v);
        }
    }
}

// ---------------------------------------------------------------------------
// Kernel 2: histogram of chosen NN indices per (dir, batch).
// ---------------------------------------------------------------------------
__global__ __launch_bounds__(TPB) void k_count(const unsigned int* __restrict__ pk,
                                               unsigned int* __restrict__ cnt) {
    const int gid = blockIdx.x * TPB + threadIdx.x;      // 0 .. 2*NQ-1
    const unsigned idx = pk[gid] & 0xFFFu;
    atomicAdd(&cnt[((unsigned)(gid >> 12) << 12) + idx], 1u);
}

// ---------------------------------------------------------------------------
// Kernel 3: per-query loss term + block partial sums (deterministic tree).
// dist recomputed exactly (fp32) from gathered NN, matching the reference.
// ---------------------------------------------------------------------------
__device__ inline float block_reduce_sum(float v) {
    for (int o = 32; o > 0; o >>= 1) v += __shfl_down(v, o, 64);
    __shared__ float wsum[TPB / 64];
    const int lane = threadIdx.x & 63;
    const int w    = threadIdx.x >> 6;
    if (lane == 0) wsum[w] = v;
    __syncthreads();
    float r = 0.0f;
    if (threadIdx.x == 0) {
#pragma unroll
        for (int i = 0; i < TPB / 64; ++i) r += wsum[i];
    }
    return r;
}

__global__ __launch_bounds__(TPB) void k_loss(const float* __restrict__ xyz1,
                                              const float* __restrict__ xyz2,
                                              const unsigned int* __restrict__ pk,
                                              const unsigned int* __restrict__ cnt,
                                              float* __restrict__ part) {
    const int gid = blockIdx.x * TPB + threadIdx.x;      // 0 .. 2*NQ-1
    const int dir = gid >> 15;
    const int rem = gid & (NQ - 1);
    const int b   = rem >> 12;
    const int i   = rem & (NN - 1);

    const float* __restrict__ Qp = dir ? xyz2 : xyz1;
    const float* __restrict__ Rp = dir ? xyz1 : xyz2;

    const unsigned idx = pk[gid] & 0xFFFu;

    const float* q = Qp + ((size_t)b * NN + i) * 3;
    const float* r = Rp + ((size_t)b * NN + idx) * 3;
    const float dx = q[0] - r[0];
    const float dy = q[1] - r[1];
    const float dz = q[2] - r[2];
    const float d  = dx * dx + dy * dy + dz * dz;

    const float w    = 1.0f / ((float)cnt[((unsigned)(gid >> 12) << 12) + idx] + EPS);
    const float term = 1.0f - expf(-ALPHA * d) * w;

    const float s = block_reduce_sum(term);
    if (threadIdx.x == 0) part[blockIdx.x] = s;
}

// ---------------------------------------------------------------------------
// Kernel 4: final reduction of 256 partials -> scalar mean.
// ---------------------------------------------------------------------------
__global__ __launch_bounds__(TPB) void k_final(const float* __restrict__ part,
                                               float* __restrict__ out) {
    float v = part[threadIdx.x];                 // exactly 256 partials
    const float s = block_reduce_sum(v);
    if (threadIdx.x == 0) out[0] = s * (1.0f / (float)(2 * NQ));
}

// ---------------------------------------------------------------------------
extern "C" void kernel_launch(void* const* d_in, const int* in_sizes, int n_in,
                              void* d_out, int out_size, void* d_ws, size_t ws_size,
                              hipStream_t stream) {
    const float* xyz1 = (const float*)d_in[0];
    const float* xyz2 = (const float*)d_in[1];
    float* out = (float*)d_out;

    // workspace layout (~2.5 MiB)
    char* ws = (char*)d_ws;
    unsigned int*   pk   = (unsigned int*)ws;                       // 256 KiB
    unsigned int*   cnt  = (unsigned int*)(ws + 262144);            // 256 KiB
    float*          prt  = (float*)(ws + 524288);                   // 4 KiB reserved
    unsigned short* Amat = (unsigned short*)(ws + 528384);          // 1 MiB
    unsigned short* Bmat = (unsigned short*)(ws + 528384 + 1048576);// 1 MiB

    k_prep<<<(2 * NQ) / TPB, TPB, 0, stream>>>(xyz1, xyz2, Amat, Bmat, pk, cnt);
    k_argmin<<<dim3(16, 16, BB), TPB, 0, stream>>>(Amat, Bmat, pk);
    k_count<<<(2 * NQ) / TPB, TPB, 0, stream>>>(pk, cnt);
    k_loss<<<(2 * NQ) / TPB, TPB, 0, stream>>>(xyz1, xyz2, pk, cnt, prt);
    k_final<<<1, TPB, 0, stream>>>(prt, out);
}